// Round 2
// baseline (11342.765 us; speedup 1.0000x reference)
//
#include <hip/hip_runtime.h>
#include <stdint.h>

// Problem constants (fixed by the reference)
#define NNODES   100000
#define DIN      512
#define DOUT     256

// ---------------------------------------------------------------------------
// JAX threefry2x32 with key = jax.random.key(42) -> (k0,k1) = (0, 42)
// ks2 = k0 ^ k1 ^ 0x1BD11BDA = 0x1BD11BF0
// ---------------------------------------------------------------------------
__device__ __forceinline__ void threefry_0_42(uint32_t c0, uint32_t c1,
                                              uint32_t& o0, uint32_t& o1) {
  const uint32_t ks0 = 0u, ks1 = 42u, ks2 = 0x1BD11BF0u;
  uint32_t x0 = c0 + ks0;
  uint32_t x1 = c1 + ks1;
#define TF_R(r) { x0 += x1; x1 = (x1 << (r)) | (x1 >> (32 - (r))); x1 ^= x0; }
  TF_R(13) TF_R(15) TF_R(26) TF_R(6)
  x0 += ks1; x1 += ks2 + 1u;
  TF_R(17) TF_R(29) TF_R(16) TF_R(24)
  x0 += ks2; x1 += ks0 + 2u;
  TF_R(13) TF_R(15) TF_R(26) TF_R(6)
  x0 += ks0; x1 += ks1 + 3u;
  TF_R(17) TF_R(29) TF_R(16) TF_R(24)
  x0 += ks1; x1 += ks2 + 4u;
  TF_R(13) TF_R(15) TF_R(26) TF_R(6)
  x0 += ks2; x1 += ks0 + 5u;
#undef TF_R
  o0 = x0; o1 = x1;
}

// dropout(x) for flat element index idx = n*DIN + k, matching
// jax.random.bernoulli(key(42), 0.9, (N, DIN)) under the MODERN default
// jax_threefry_partitionable=True (JAX >= 0.4.30):
//   counts = iota(uint64, size); (o0,o1) = threefry(key, (hi32(i), lo32(i)))
//   bits = o0 ^ o1      (32-bit output xor-fold)
// size = 51.2M < 2^32 -> counter is (0, idx).
__device__ __forceinline__ float dropout_apply(float x, uint32_t idx) {
  uint32_t r0, r1;
  threefry_0_42(0u, idx, r0, r1);
  uint32_t bits = r0 ^ r1;
  // jax.random.uniform fp32: bitcast(bits>>9 | 0x3f800000) - 1.0
  float u = __uint_as_float((bits >> 9) | 0x3F800000u) - 1.0f;
  return (u < 0.9f) ? x * (1.0f / 0.9f) : 0.0f;
}

// ---------------------------------------------------------------------------
// Kernel 1: fused dropout + fp32 GEMM  h[N,256] = dropout(x)[N,512] @ W[512,256]
// Block: 256 threads, tile = 64 rows x 256 cols (all cols -> RNG once/element).
// K staged in chunks of 16 through LDS. Each thread: 4 rows x 16 cols.
// ---------------------------------------------------------------------------
__launch_bounds__(256, 2)
__global__ void dropout_gemm(const float* __restrict__ x,
                             const float* __restrict__ W,
                             float* __restrict__ h) {
  __shared__ float As[16][68];    // [kk][row], stride 68 (pad: conflict-free b128 reads)
  __shared__ float Bs[16][260];   // [kk][col], stride 260

  const int tid = threadIdx.x;
  const int n0  = blockIdx.x * 64;
  const int cg  = tid & 15;       // col group: cols cg*4 + 64*j4 + jj
  const int rg  = tid >> 4;       // row group: rows rg*4 + rr
  const int arow = tid >> 2;      // A staging: row 0..63
  const int ak4  = (tid & 3) << 2; // A staging: k offset 0,4,8,12
  const int bkk  = tid >> 4;      // B staging: k row 0..15

  float acc[4][16];
#pragma unroll
  for (int r = 0; r < 4; ++r)
#pragma unroll
    for (int c = 0; c < 16; ++c) acc[r][c] = 0.0f;

  for (int k0 = 0; k0 < DIN; k0 += 16) {
    // ---- stage A (with dropout): 64x16 ----
    {
      int n = n0 + arow;
      float4 xv = make_float4(0.f, 0.f, 0.f, 0.f);
      if (n < NNODES)
        xv = *(const float4*)(x + (size_t)n * DIN + k0 + ak4);
      uint32_t base = (uint32_t)n * DIN + (uint32_t)(k0 + ak4);
      // OOB rows: xv==0 -> dropout_apply returns 0 either way
      As[ak4 + 0][arow] = dropout_apply(xv.x, base + 0u);
      As[ak4 + 1][arow] = dropout_apply(xv.y, base + 1u);
      As[ak4 + 2][arow] = dropout_apply(xv.z, base + 2u);
      As[ak4 + 3][arow] = dropout_apply(xv.w, base + 3u);
    }
    // ---- stage B: 16x256 ----
    {
      const float* wrow = W + (size_t)(k0 + bkk) * DOUT + (cg << 2);
#pragma unroll
      for (int j4 = 0; j4 < 4; ++j4) {
        float4 wv = *(const float4*)(wrow + 64 * j4);
        *(float4*)&Bs[bkk][(cg << 2) + 64 * j4] = wv;
      }
    }
    __syncthreads();

#pragma unroll
    for (int kk = 0; kk < 16; ++kk) {
      float4 av  = *(const float4*)&As[kk][rg << 2];
      float4 bv0 = *(const float4*)&Bs[kk][(cg << 2) + 0];
      float4 bv1 = *(const float4*)&Bs[kk][(cg << 2) + 64];
      float4 bv2 = *(const float4*)&Bs[kk][(cg << 2) + 128];
      float4 bv3 = *(const float4*)&Bs[kk][(cg << 2) + 192];
      const float a[4]  = {av.x, av.y, av.z, av.w};
      const float b[16] = {bv0.x, bv0.y, bv0.z, bv0.w,
                           bv1.x, bv1.y, bv1.z, bv1.w,
                           bv2.x, bv2.y, bv2.z, bv2.w,
                           bv3.x, bv3.y, bv3.z, bv3.w};
#pragma unroll
      for (int r = 0; r < 4; ++r)
#pragma unroll
        for (int c = 0; c < 16; ++c) acc[r][c] = fmaf(a[r], b[c], acc[r][c]);
    }
    __syncthreads();
  }

  // ---- store h ----
#pragma unroll
  for (int rr = 0; rr < 4; ++rr) {
    int n = n0 + (rg << 2) + rr;
    if (n < NNODES) {
#pragma unroll
      for (int j4 = 0; j4 < 4; ++j4) {
        float4 v = make_float4(acc[rr][j4 * 4 + 0], acc[rr][j4 * 4 + 1],
                               acc[rr][j4 * 4 + 2], acc[rr][j4 * 4 + 3]);
        *(float4*)(h + (size_t)n * DOUT + (cg << 2) + 64 * j4) = v;
      }
    }
  }
}

// ---------------------------------------------------------------------------
// Kernel 2: edge scatter: out[dst] += w_e * h[src], one wave per edge.
// 64 lanes x float4 = 256 floats per edge. fp32 global atomics (device scope).
// ---------------------------------------------------------------------------
__launch_bounds__(256)
__global__ void scatter_edges(const float* __restrict__ h,
                              const int* __restrict__ esrc,
                              const int* __restrict__ edst,
                              const float* __restrict__ ew,
                              float* __restrict__ out, int E) {
  const int lane   = threadIdx.x & 63;
  const int wave0  = (blockIdx.x * blockDim.x + threadIdx.x) >> 6;
  const int nwaves = (gridDim.x * blockDim.x) >> 6;
  for (int e = wave0; e < E; e += nwaves) {
    int s = esrc[e];
    int d = edst[e];
    float w = ew[e];
    float4 v = *(const float4*)(h + (size_t)s * DOUT + (lane << 2));
    float* o = out + (size_t)d * DOUT + (lane << 2);
    atomicAdd(o + 0, w * v.x);
    atomicAdd(o + 1, w * v.y);
    atomicAdd(o + 2, w * v.z);
    atomicAdd(o + 3, w * v.w);
  }
}

// ---------------------------------------------------------------------------
// Kernel 3: in-place ReLU on out
// ---------------------------------------------------------------------------
__launch_bounds__(256)
__global__ void relu_kernel(float* __restrict__ out, int n4) {
  int i = blockIdx.x * blockDim.x + threadIdx.x;
  if (i < n4) {
    float4 v = ((float4*)out)[i];
    v.x = fmaxf(v.x, 0.f);
    v.y = fmaxf(v.y, 0.f);
    v.z = fmaxf(v.z, 0.f);
    v.w = fmaxf(v.w, 0.f);
    ((float4*)out)[i] = v;
  }
}

extern "C" void kernel_launch(void* const* d_in, const int* in_sizes, int n_in,
                              void* d_out, int out_size, void* d_ws, size_t ws_size,
                              hipStream_t stream) {
  const float* x   = (const float*)d_in[0];
  const float* W   = (const float*)d_in[1];
  const int* esrc  = (const int*)d_in[2];
  const int* edst  = (const int*)d_in[3];
  const float* ew  = (const float*)d_in[4];
  float* out = (float*)d_out;
  float* h   = (float*)d_ws;          // 100000*256 fp32 = 102.4 MB scratch
  const int E = in_sizes[2];

  // out accumulates atomics -> must start at zero (harness poisons with 0xAA)
  hipMemsetAsync(d_out, 0, (size_t)out_size * sizeof(float), stream);

  dropout_gemm<<<(NNODES + 63) / 64, 256, 0, stream>>>(x, W, h);

  // 100k blocks -> 400k waves, 8 edges per wave
  scatter_edges<<<100000, 256, 0, stream>>>(h, esrc, edst, ew, out, E);

  int n4 = out_size / 4;
  relu_kernel<<<(n4 + 255) / 256, 256, 0, stream>>>(out, n4);
}

// Round 3
// 1675.135 us; speedup vs baseline: 6.7713x; 6.7713x over previous
//
#include <hip/hip_runtime.h>
#include <stdint.h>

// Problem constants (fixed by the reference)
#define NNODES   100000
#define DIN      512
#define DOUT     256

// ---------------------------------------------------------------------------
// JAX threefry2x32, key = jax.random.key(42) -> (0, 42); ks2 = 0x1BD11BF0
// Modern default jax_threefry_partitionable=True: bits(i) = o0^o1 of
// threefry(key, (0, i)) for size < 2^32.
// ---------------------------------------------------------------------------
__device__ __forceinline__ void threefry_0_42(uint32_t c0, uint32_t c1,
                                              uint32_t& o0, uint32_t& o1) {
  const uint32_t ks0 = 0u, ks1 = 42u, ks2 = 0x1BD11BF0u;
  uint32_t x0 = c0 + ks0;
  uint32_t x1 = c1 + ks1;
#define TF_R(r) { x0 += x1; x1 = (x1 << (r)) | (x1 >> (32 - (r))); x1 ^= x0; }
  TF_R(13) TF_R(15) TF_R(26) TF_R(6)
  x0 += ks1; x1 += ks2 + 1u;
  TF_R(17) TF_R(29) TF_R(16) TF_R(24)
  x0 += ks2; x1 += ks0 + 2u;
  TF_R(13) TF_R(15) TF_R(26) TF_R(6)
  x0 += ks0; x1 += ks1 + 3u;
  TF_R(17) TF_R(29) TF_R(16) TF_R(24)
  x0 += ks1; x1 += ks2 + 4u;
  TF_R(13) TF_R(15) TF_R(26) TF_R(6)
  x0 += ks2; x1 += ks0 + 5u;
#undef TF_R
  o0 = x0; o1 = x1;
}

__device__ __forceinline__ float dropout_apply(float x, uint32_t idx) {
  uint32_t r0, r1;
  threefry_0_42(0u, idx, r0, r1);
  uint32_t bits = r0 ^ r1;
  float u = __uint_as_float((bits >> 9) | 0x3F800000u) - 1.0f;
  return (u < 0.9f) ? x * (1.0f / 0.9f) : 0.0f;
}

// ---------------------------------------------------------------------------
// Kernel 1: fused dropout + fp32 GEMM  h[N,256] = dropout(x)[N,512] @ W[512,256]
// ---------------------------------------------------------------------------
__launch_bounds__(256, 2)
__global__ void dropout_gemm(const float* __restrict__ x,
                             const float* __restrict__ W,
                             float* __restrict__ h) {
  __shared__ float As[16][68];
  __shared__ float Bs[16][260];

  const int tid = threadIdx.x;
  const int n0  = blockIdx.x * 64;
  const int cg  = tid & 15;
  const int rg  = tid >> 4;
  const int arow = tid >> 2;
  const int ak4  = (tid & 3) << 2;
  const int bkk  = tid >> 4;

  float acc[4][16];
#pragma unroll
  for (int r = 0; r < 4; ++r)
#pragma unroll
    for (int c = 0; c < 16; ++c) acc[r][c] = 0.0f;

  for (int k0 = 0; k0 < DIN; k0 += 16) {
    {
      int n = n0 + arow;
      float4 xv = make_float4(0.f, 0.f, 0.f, 0.f);
      if (n < NNODES)
        xv = *(const float4*)(x + (size_t)n * DIN + k0 + ak4);
      uint32_t base = (uint32_t)n * DIN + (uint32_t)(k0 + ak4);
      As[ak4 + 0][arow] = dropout_apply(xv.x, base + 0u);
      As[ak4 + 1][arow] = dropout_apply(xv.y, base + 1u);
      As[ak4 + 2][arow] = dropout_apply(xv.z, base + 2u);
      As[ak4 + 3][arow] = dropout_apply(xv.w, base + 3u);
    }
    {
      const float* wrow = W + (size_t)(k0 + bkk) * DOUT + (cg << 2);
#pragma unroll
      for (int j4 = 0; j4 < 4; ++j4) {
        float4 wv = *(const float4*)(wrow + 64 * j4);
        *(float4*)&Bs[bkk][(cg << 2) + 64 * j4] = wv;
      }
    }
    __syncthreads();

#pragma unroll
    for (int kk = 0; kk < 16; ++kk) {
      float4 av  = *(const float4*)&As[kk][rg << 2];
      float4 bv0 = *(const float4*)&Bs[kk][(cg << 2) + 0];
      float4 bv1 = *(const float4*)&Bs[kk][(cg << 2) + 64];
      float4 bv2 = *(const float4*)&Bs[kk][(cg << 2) + 128];
      float4 bv3 = *(const float4*)&Bs[kk][(cg << 2) + 192];
      const float a[4]  = {av.x, av.y, av.z, av.w};
      const float b[16] = {bv0.x, bv0.y, bv0.z, bv0.w,
                           bv1.x, bv1.y, bv1.z, bv1.w,
                           bv2.x, bv2.y, bv2.z, bv2.w,
                           bv3.x, bv3.y, bv3.z, bv3.w};
#pragma unroll
      for (int r = 0; r < 4; ++r)
#pragma unroll
        for (int c = 0; c < 16; ++c) acc[r][c] = fmaf(a[r], b[c], acc[r][c]);
    }
    __syncthreads();
  }

#pragma unroll
  for (int rr = 0; rr < 4; ++rr) {
    int n = n0 + (rg << 2) + rr;
    if (n < NNODES) {
#pragma unroll
      for (int j4 = 0; j4 < 4; ++j4) {
        float4 v = make_float4(acc[rr][j4 * 4 + 0], acc[rr][j4 * 4 + 1],
                               acc[rr][j4 * 4 + 2], acc[rr][j4 * 4 + 3]);
        *(float4*)(h + (size_t)n * DOUT + (cg << 2) + 64 * j4) = v;
      }
    }
  }
}

// ---------------------------------------------------------------------------
// CSR build: histogram -> single-block scan -> permute (src,w) into dst-order
// ---------------------------------------------------------------------------
__launch_bounds__(256)
__global__ void count_deg(const int* __restrict__ edst, int* __restrict__ counts, int E) {
  int e = blockIdx.x * blockDim.x + threadIdx.x;
  if (e < E) atomicAdd(&counts[edst[e]], 1);
}

// Exclusive scan of counts[0..N) into offsets[0..N). One block, 1024 threads,
// each thread serially handles CHUNK contiguous elements.
#define SCAN_T 1024
#define SCAN_CHUNK 98   // 1024*98 = 100352 >= 100000
__launch_bounds__(SCAN_T)
__global__ void scan_counts(const int* __restrict__ counts, int* __restrict__ offsets, int n) {
  __shared__ int sums[SCAN_T];
  const int t = threadIdx.x;
  const int base = t * SCAN_CHUNK;
  int my = 0;
#pragma unroll 1
  for (int i = 0; i < SCAN_CHUNK; ++i) {
    int idx = base + i;
    if (idx < n) my += counts[idx];
  }
  sums[t] = my;
  __syncthreads();
  // Hillis-Steele inclusive scan
  for (int off = 1; off < SCAN_T; off <<= 1) {
    int v = (t >= off) ? sums[t - off] : 0;
    __syncthreads();
    sums[t] += v;
    __syncthreads();
  }
  int running = sums[t] - my;   // exclusive prefix for this thread's chunk
#pragma unroll 1
  for (int i = 0; i < SCAN_CHUNK; ++i) {
    int idx = base + i;
    if (idx < n) {
      offsets[idx] = running;
      running += counts[idx];
    }
  }
}

// Bump offsets[d] atomically; afterwards offsets[d] == inclusive prefix (end of bucket d).
__launch_bounds__(256)
__global__ void fill_pairs(const int* __restrict__ esrc, const int* __restrict__ edst,
                           const float* __restrict__ ew, int* __restrict__ offsets,
                           int2* __restrict__ pairs, int E) {
  int e = blockIdx.x * blockDim.x + threadIdx.x;
  if (e < E) {
    int d = edst[e];
    int pos = atomicAdd(&offsets[d], 1);
    pairs[pos] = make_int2(esrc[e], __float_as_int(ew[e]));
  }
}

// ---------------------------------------------------------------------------
// Kernel 2: gather-reduce, one wave per dst node. offs[] is post-fill
// (inclusive): start = offs[d-1] (0 for d=0), end = offs[d]. Fused ReLU.
// ---------------------------------------------------------------------------
__launch_bounds__(256)
__global__ void gather_reduce(const float* __restrict__ h,
                              const int* __restrict__ offs,
                              const int2* __restrict__ pairs,
                              float* __restrict__ out) {
  const int wave = blockIdx.x * (blockDim.x >> 6) + (threadIdx.x >> 6);
  const int lane = threadIdx.x & 63;
  if (wave >= NNODES) return;
  const int start = (wave == 0) ? 0 : offs[wave - 1];
  const int end   = offs[wave];

  float4 a0 = make_float4(0.f, 0.f, 0.f, 0.f);
  float4 a1 = make_float4(0.f, 0.f, 0.f, 0.f);
  int j = start;
  for (; j + 2 <= end; j += 2) {
    int2 p0 = pairs[j];
    int2 p1 = pairs[j + 1];
    float4 v0 = *(const float4*)(h + (size_t)p0.x * DOUT + (lane << 2));
    float4 v1 = *(const float4*)(h + (size_t)p1.x * DOUT + (lane << 2));
    float w0 = __int_as_float(p0.y);
    float w1 = __int_as_float(p1.y);
    a0.x = fmaf(w0, v0.x, a0.x); a0.y = fmaf(w0, v0.y, a0.y);
    a0.z = fmaf(w0, v0.z, a0.z); a0.w = fmaf(w0, v0.w, a0.w);
    a1.x = fmaf(w1, v1.x, a1.x); a1.y = fmaf(w1, v1.y, a1.y);
    a1.z = fmaf(w1, v1.z, a1.z); a1.w = fmaf(w1, v1.w, a1.w);
  }
  if (j < end) {
    int2 p0 = pairs[j];
    float4 v0 = *(const float4*)(h + (size_t)p0.x * DOUT + (lane << 2));
    float w0 = __int_as_float(p0.y);
    a0.x = fmaf(w0, v0.x, a0.x); a0.y = fmaf(w0, v0.y, a0.y);
    a0.z = fmaf(w0, v0.z, a0.z); a0.w = fmaf(w0, v0.w, a0.w);
  }
  float4 r;
  r.x = fmaxf(a0.x + a1.x, 0.f);
  r.y = fmaxf(a0.y + a1.y, 0.f);
  r.z = fmaxf(a0.z + a1.z, 0.f);
  r.w = fmaxf(a0.w + a1.w, 0.f);
  *(float4*)(out + (size_t)wave * DOUT + (lane << 2)) = r;
}

// ---------------------------------------------------------------------------
// Fallback path (ws too small): atomic scatter + relu
// ---------------------------------------------------------------------------
__launch_bounds__(256)
__global__ void scatter_edges(const float* __restrict__ h,
                              const int* __restrict__ esrc,
                              const int* __restrict__ edst,
                              const float* __restrict__ ew,
                              float* __restrict__ out, int E) {
  const int lane   = threadIdx.x & 63;
  const int wave0  = (blockIdx.x * blockDim.x + threadIdx.x) >> 6;
  const int nwaves = (gridDim.x * blockDim.x) >> 6;
  for (int e = wave0; e < E; e += nwaves) {
    int s = esrc[e];
    int d = edst[e];
    float w = ew[e];
    float4 v = *(const float4*)(h + (size_t)s * DOUT + (lane << 2));
    float* o = out + (size_t)d * DOUT + (lane << 2);
    atomicAdd(o + 0, w * v.x);
    atomicAdd(o + 1, w * v.y);
    atomicAdd(o + 2, w * v.z);
    atomicAdd(o + 3, w * v.w);
  }
}

__launch_bounds__(256)
__global__ void relu_kernel(float* __restrict__ out, int n4) {
  int i = blockIdx.x * blockDim.x + threadIdx.x;
  if (i < n4) {
    float4 v = ((float4*)out)[i];
    v.x = fmaxf(v.x, 0.f);
    v.y = fmaxf(v.y, 0.f);
    v.z = fmaxf(v.z, 0.f);
    v.w = fmaxf(v.w, 0.f);
    ((float4*)out)[i] = v;
  }
}

extern "C" void kernel_launch(void* const* d_in, const int* in_sizes, int n_in,
                              void* d_out, int out_size, void* d_ws, size_t ws_size,
                              hipStream_t stream) {
  const float* x   = (const float*)d_in[0];
  const float* W   = (const float*)d_in[1];
  const int* esrc  = (const int*)d_in[2];
  const int* edst  = (const int*)d_in[3];
  const float* ew  = (const float*)d_in[4];
  float* out = (float*)d_out;
  const int E = in_sizes[2];

  // workspace layout
  char* ws = (char*)d_ws;
  const size_t h_off      = 0;
  const size_t h_bytes    = (size_t)NNODES * DOUT * sizeof(float);     // 102,400,000
  const size_t counts_off = h_off + h_bytes;                            // 256-aligned
  const size_t cnt_bytes  = (size_t)NNODES * sizeof(int);
  const size_t offs_off   = counts_off + ((cnt_bytes + 255) & ~255ull);
  const size_t pairs_off  = offs_off + ((cnt_bytes + 255) & ~255ull);
  const size_t need       = pairs_off + (size_t)E * sizeof(int2);

  float* h = (float*)(ws + h_off);

  dropout_gemm<<<(NNODES + 63) / 64, 256, 0, stream>>>(x, W, h);

  if (ws_size >= need) {
    int* counts  = (int*)(ws + counts_off);
    int* offsets = (int*)(ws + offs_off);
    int2* pairs  = (int2*)(ws + pairs_off);

    hipMemsetAsync(counts, 0, cnt_bytes, stream);
    count_deg<<<(E + 255) / 256, 256, 0, stream>>>(edst, counts, E);
    scan_counts<<<1, SCAN_T, 0, stream>>>(counts, offsets, NNODES);
    fill_pairs<<<(E + 255) / 256, 256, 0, stream>>>(esrc, edst, ew, offsets, pairs, E);
    // 4 waves (nodes) per 256-thread block
    gather_reduce<<<(NNODES + 3) / 4, 256, 0, stream>>>(h, offsets, pairs, out);
  } else {
    // fallback: atomic scatter (out must start at zero)
    hipMemsetAsync(d_out, 0, (size_t)out_size * sizeof(float), stream);
    scatter_edges<<<100000, 256, 0, stream>>>(h, esrc, edst, ew, out, E);
    int n4 = out_size / 4;
    relu_kernel<<<(n4 + 255) / 256, 256, 0, stream>>>(out, n4);
  }
}